// Round 3
// baseline (570.042 us; speedup 1.0000x reference)
//
#include <hip/hip_runtime.h>

#define BLK 256

// ---------------------------------------------------------------- zero
__global__ void k_zero(int* __restrict__ cnt, float* __restrict__ acc, int N, int B) {
    int i = blockIdx.x * BLK + threadIdx.x;
    if (i < N) cnt[i] = 0;
    if (i < B) acc[i] = 0.0f;
}

// cnt[dst] += 1 per edge (int in-degree)
__global__ void k_count(const int* __restrict__ dst, int* __restrict__ cnt, int E) {
    int i = blockIdx.x * BLK + threadIdx.x;
    if (i < E) atomicAdd(&cnt[dst[i]], 1);
}

// ---------------------------------------------------------------- scan (exclusive, 2-level)
__global__ void k_scan1(const int* __restrict__ cnt, int* __restrict__ rs,
                        int* __restrict__ bsum, int N) {
    __shared__ int s[BLK];
    int i = blockIdx.x * BLK + threadIdx.x;
    int v = (i < N) ? cnt[i] : 0;
    s[threadIdx.x] = v;
    __syncthreads();
    for (int off = 1; off < BLK; off <<= 1) {
        int t = (threadIdx.x >= off) ? s[threadIdx.x - off] : 0;
        __syncthreads();
        s[threadIdx.x] += t;
        __syncthreads();
    }
    if (i < N) rs[i] = s[threadIdx.x] - v;  // exclusive within block
    if (threadIdx.x == BLK - 1) bsum[blockIdx.x] = s[BLK - 1];
}

__global__ void k_scan2(int* __restrict__ bsum, int nb) {
    if (threadIdx.x == 0) {
        int r = 0;
        for (int i = 0; i < nb; ++i) { int t = bsum[i]; bsum[i] = r; r += t; }
    }
}

__global__ void k_scan3(int* __restrict__ rs, int* __restrict__ cur,
                        const int* __restrict__ bsum, int N) {
    int i = blockIdx.x * BLK + threadIdx.x;
    if (i < N) {
        int v = rs[i] + bsum[blockIdx.x];
        rs[i] = v;
        cur[i] = v;
    }
}

// ---------------------------------------------------------------- CSR fill
__global__ void k_fill(const int* __restrict__ src, const int* __restrict__ dst,
                       const int* __restrict__ cnt, int* __restrict__ cur,
                       int* __restrict__ csrc, float* __restrict__ cw, int E) {
    int e = blockIdx.x * BLK + threadIdx.x;
    if (e >= E) return;
    int d = dst[e], s = src[e];
    int p = atomicAdd(&cur[d], 1);
    csrc[p] = s;
    cw[p] = rsqrtf((1.0f + (float)cnt[s]) * (1.0f + (float)cnt[d]));
}

// ---------------------------------------------------------------- GEMM
// C[M][64] = A[M][K] @ W[K][64]; row-major throughout. 128-row tile,
// 256 threads, 8x4 register blocking, K staged in 64-chunks.
template <int K, bool RELU>
__global__ __launch_bounds__(BLK) void k_gemm(const float* __restrict__ A,
                                              const float* __restrict__ W,
                                              float* __restrict__ C, int M) {
    __shared__ float As[128 * 65];  // padded: row r at As[r*65]
    __shared__ float Bs[64 * 64];   // one 64-K chunk of W
    const int t = threadIdx.x;
    const int row0 = blockIdx.x * 128;
    const int tx = t & 15, ty = t >> 4;   // tx: col group (4 cols), ty: row group (8 rows)

    float acc[8][4] = {};

    for (int kk = 0; kk < K; kk += 64) {
        if (kk) __syncthreads();
        // stage A[row0..row0+127][kk..kk+63] -> As[128][65]
        for (int i = t; i < 128 * 16; i += BLK) {
            int r = i >> 4, c = i & 15;
            int gr = row0 + r;
            float4 v = make_float4(0.f, 0.f, 0.f, 0.f);
            if (gr < M)
                v = *reinterpret_cast<const float4*>(A + (size_t)gr * K + kk + c * 4);
            if (RELU) {
                v.x = fmaxf(v.x, 0.f); v.y = fmaxf(v.y, 0.f);
                v.z = fmaxf(v.z, 0.f); v.w = fmaxf(v.w, 0.f);
            }
            *reinterpret_cast<float4*>(As + r * 65 + c * 4) = v;
        }
        // stage W[kk..kk+63][0..63] -> Bs
        for (int i = t; i < 64 * 16; i += BLK) {
            int r = i >> 4, c = i & 15;
            *reinterpret_cast<float4*>(Bs + r * 64 + c * 4) =
                *reinterpret_cast<const float4*>(W + (size_t)(kk + r) * 64 + c * 4);
        }
        __syncthreads();

        #pragma unroll 4
        for (int k2 = 0; k2 < 64; ++k2) {
            float4 bv = *reinterpret_cast<const float4*>(Bs + k2 * 64 + tx * 4);
            float a[8];
            #pragma unroll
            for (int i = 0; i < 8; ++i) a[i] = As[(ty * 8 + i) * 65 + k2];
            #pragma unroll
            for (int i = 0; i < 8; ++i) {
                acc[i][0] = fmaf(a[i], bv.x, acc[i][0]);
                acc[i][1] = fmaf(a[i], bv.y, acc[i][1]);
                acc[i][2] = fmaf(a[i], bv.z, acc[i][2]);
                acc[i][3] = fmaf(a[i], bv.w, acc[i][3]);
            }
        }
    }

    #pragma unroll
    for (int i = 0; i < 8; ++i) {
        int gr = row0 + ty * 8 + i;
        if (gr < M) {
            float4 v = make_float4(acc[i][0], acc[i][1], acc[i][2], acc[i][3]);
            *reinterpret_cast<float4*>(C + (size_t)gr * 64 + tx * 4) = v;
        }
    }
}

// ---------------------------------------------------------------- gather aggregate
// Layout [B][N][64]. One wave per (dst node, batch); lane = channel.
// Blocks ordered batch-major so co-resident blocks share the 5.1MB batch slice (L2).
// agg[b][n] = sum_e w_e * hw[b][src_e] + hw[b][n]/(1+deg) + bias
__global__ __launch_bounds__(BLK) void k_gather(const float* __restrict__ hw,
                                                const int* __restrict__ rs,
                                                const int* __restrict__ cnt,
                                                const int* __restrict__ csrc,
                                                const float* __restrict__ cw,
                                                const float* __restrict__ bias,
                                                float* __restrict__ agg,
                                                int N, int chunksPerB) {
    int b = blockIdx.x / chunksPerB;
    int chunk = blockIdx.x % chunksPerB;
    int wv = threadIdx.x >> 6, lane = threadIdx.x & 63;
    int n = chunk * 4 + wv;
    if (n >= N) return;
    const float* hwb = hw + (size_t)b * N * 64;
    int beg = rs[n];
    int deg = cnt[n];
    float a = fmaf(hwb[(size_t)n * 64 + lane], 1.0f / (1.0f + (float)deg), bias[lane]);
    int i = 0;
    for (; i + 2 <= deg; i += 2) {
        int s0 = csrc[beg + i], s1 = csrc[beg + i + 1];
        float w0 = cw[beg + i], w1 = cw[beg + i + 1];
        float v0 = hwb[(size_t)s0 * 64 + lane];
        float v1 = hwb[(size_t)s1 * 64 + lane];
        a = fmaf(w0, v0, a);
        a = fmaf(w1, v1, a);
    }
    if (i < deg)
        a = fmaf(cw[beg + i], hwb[(size_t)csrc[beg + i] * 64 + lane], a);
    agg[(size_t)b * N * 64 + (size_t)n * 64 + lane] = a;
}

// ---------------------------------------------------------------- pooled dot
// acc[b] += sum_n sum_h relu(agg2[b,n,h]) * fcw[h]
__global__ void k_reduce(const float* __restrict__ agg2, const float* __restrict__ fcw,
                         float* __restrict__ acc, int N, int chunks) {
    int b = blockIdx.x / chunks;
    int chunk = blockIdx.x % chunks;
    int lane = threadIdx.x & 63;
    int w = threadIdx.x >> 6;
    int wave = chunk * (BLK >> 6) + w;
    int nwaves = chunks * (BLK >> 6);
    float fw = fcw[lane];
    float p = 0.f;
    const float* base = agg2 + (size_t)b * N * 64 + lane;
    for (int n = wave; n < N; n += nwaves)
        p += fmaxf(base[(size_t)n * 64], 0.f) * fw;
    #pragma unroll
    for (int off = 32; off; off >>= 1) p += __shfl_down(p, off, 64);
    if (lane == 0) atomicAdd(&acc[b], p);
}

__global__ void k_out(const float* __restrict__ acc, const float* __restrict__ addf,
                      const float* __restrict__ fcw, const float* __restrict__ fcb,
                      float* __restrict__ out, int N, int B, int H) {
    int b = threadIdx.x;
    if (b < B) out[b] = acc[b] / (float)N + addf[b] * fcw[H] + fcb[0];
}

// ---------------------------------------------------------------- launch
extern "C" void kernel_launch(void* const* d_in, const int* in_sizes, int n_in,
                              void* d_out, int out_size, void* d_ws, size_t ws_size,
                              hipStream_t stream) {
    const float* x    = (const float*)d_in[0];
    const float* addf = (const float*)d_in[1];
    const int*   ei   = (const int*)d_in[2];
    const float* W1   = (const float*)d_in[3];
    const float* b1   = (const float*)d_in[4];
    const float* W2   = (const float*)d_in[5];
    const float* b2   = (const float*)d_in[6];
    const float* fcw  = (const float*)d_in[7];
    const float* fcb  = (const float*)d_in[8];
    float* out = (float*)d_out;

    const int B  = in_sizes[1];            // 8
    const int H  = in_sizes[4];            // 64
    const int IN = in_sizes[3] / H;        // 128
    const int E  = in_sizes[2] / 2;        // 320000
    const int N  = in_sizes[0] / (B * IN); // 20000
    const int* src = ei;
    const int* dst = ei + E;

    const int M = B * N;                   // 160000 rows

    float* ws = (float*)d_ws;
    size_t bufsz = (size_t)M * H;          // 10.24M floats
    float* bufA  = ws;                     // hw  [B][N][64]
    float* bufB  = ws + bufsz;             // agg [B][N][64]
    int*   cnt   = (int*)(bufB + bufsz);
    int*   rs    = cnt + N;
    int*   cur   = rs + N;
    int*   csrc  = cur + N;
    float* cw    = (float*)(csrc + E);
    int*   bsum  = (int*)(cw + E);
    float* acc   = (float*)(bsum + 256);

    const int nbN = (N + BLK - 1) / BLK;
    const int nbE = (E + BLK - 1) / BLK;
    const int chunksPerB = (N + 3) / 4;

    // CSR build
    k_zero<<<dim3(nbN), dim3(BLK), 0, stream>>>(cnt, acc, N, B);
    k_count<<<dim3(nbE), dim3(BLK), 0, stream>>>(dst, cnt, E);
    k_scan1<<<dim3(nbN), dim3(BLK), 0, stream>>>(cnt, rs, bsum, N);
    k_scan2<<<dim3(1), dim3(64), 0, stream>>>(bsum, nbN);
    k_scan3<<<dim3(nbN), dim3(BLK), 0, stream>>>(rs, cur, bsum, N);
    k_fill<<<dim3(nbE), dim3(BLK), 0, stream>>>(src, dst, cnt, cur, csrc, cw, E);

    // layer 1: hw1 = x @ W1 -> bufA
    k_gemm<128, false><<<dim3((M + 127) / 128), dim3(BLK), 0, stream>>>(x, W1, bufA, M);
    // agg1 = gather(hw1) + self + b1 -> bufB
    k_gather<<<dim3(B * chunksPerB), dim3(BLK), 0, stream>>>(
        bufA, rs, cnt, csrc, cw, b1, bufB, N, chunksPerB);

    // layer 2: hw2 = relu(agg1) @ W2 -> bufA
    k_gemm<64, true><<<dim3((M + 127) / 128), dim3(BLK), 0, stream>>>(bufB, W2, bufA, M);
    // agg2 = gather(hw2) + self + b2 -> bufB
    k_gather<<<dim3(B * chunksPerB), dim3(BLK), 0, stream>>>(
        bufA, rs, cnt, csrc, cw, b2, bufB, N, chunksPerB);

    // pooled dot + final linear
    const int chunks = 64;
    k_reduce<<<dim3(B * chunks), dim3(BLK), 0, stream>>>(bufB, fcw, acc, N, chunks);
    k_out<<<dim3(1), dim3(64), 0, stream>>>(acc, addf, fcw, fcb, out, N, B, H);
}

// Round 4
// 433.409 us; speedup vs baseline: 1.3153x; 1.3153x over previous
//
#include <hip/hip_runtime.h>

#define BLK 256

// ---------------------------------------------------------------- zero
__global__ void k_zero(int* __restrict__ cnt, int N) {
    int i = blockIdx.x * BLK + threadIdx.x;
    if (i < N) cnt[i] = 0;
}

// cnt[dst] += 1 per edge (int in-degree)
__global__ void k_count(const int* __restrict__ dst, int* __restrict__ cnt, int E) {
    int i = blockIdx.x * BLK + threadIdx.x;
    if (i < E) atomicAdd(&cnt[dst[i]], 1);
}

// ---------------------------------------------------------------- scan (exclusive, 2-level)
__global__ void k_scan1(const int* __restrict__ cnt, int* __restrict__ rs,
                        int* __restrict__ bsum, int N) {
    __shared__ int s[BLK];
    int i = blockIdx.x * BLK + threadIdx.x;
    int v = (i < N) ? cnt[i] : 0;
    s[threadIdx.x] = v;
    __syncthreads();
    for (int off = 1; off < BLK; off <<= 1) {
        int t = (threadIdx.x >= off) ? s[threadIdx.x - off] : 0;
        __syncthreads();
        s[threadIdx.x] += t;
        __syncthreads();
    }
    if (i < N) rs[i] = s[threadIdx.x] - v;  // exclusive within block
    if (threadIdx.x == BLK - 1) bsum[blockIdx.x] = s[BLK - 1];
}

// parallel exclusive scan of block sums (nb <= BLK fast path)
__global__ void k_scan2p(int* __restrict__ bsum, int nb) {
    __shared__ int s[BLK];
    int t = threadIdx.x;
    if (nb <= BLK) {
        int v = (t < nb) ? bsum[t] : 0;
        s[t] = v;
        __syncthreads();
        for (int off = 1; off < BLK; off <<= 1) {
            int u = (t >= off) ? s[t - off] : 0;
            __syncthreads();
            s[t] += u;
            __syncthreads();
        }
        if (t < nb) bsum[t] = s[t] - v;
    } else if (t == 0) {
        int r = 0;
        for (int i = 0; i < nb; ++i) { int x = bsum[i]; bsum[i] = r; r += x; }
    }
}

__global__ void k_scan3(int* __restrict__ rs, int* __restrict__ cur,
                        const int* __restrict__ bsum, int N) {
    int i = blockIdx.x * BLK + threadIdx.x;
    if (i < N) {
        int v = rs[i] + bsum[blockIdx.x];
        rs[i] = v;
        cur[i] = v;
    }
}

// ---------------------------------------------------------------- CSR fill
__global__ void k_fill(const int* __restrict__ src, const int* __restrict__ dst,
                       const int* __restrict__ cnt, int* __restrict__ cur,
                       int* __restrict__ csrc, float* __restrict__ cw, int E) {
    int e = blockIdx.x * BLK + threadIdx.x;
    if (e >= E) return;
    int d = dst[e], s = src[e];
    int p = atomicAdd(&cur[d], 1);
    csrc[p] = s;
    cw[p] = rsqrtf((1.0f + (float)cnt[s]) * (1.0f + (float)cnt[d]));
}

// ---------------------------------------------------------------- GEMM
// C[M][64] = A[M][K] @ W[K][64]; 128-row tile, 256 threads, 8x4 blocking.
// PIN: output rows are node-major r=n*B+b, input x is batch-major row b*N+n.
template <int K, bool RELU, bool PIN>
__global__ __launch_bounds__(BLK) void k_gemm(const float* __restrict__ A,
                                              const float* __restrict__ W,
                                              float* __restrict__ C, int M, int N, int B) {
    __shared__ float As[128 * 65];  // padded
    __shared__ float Bs[64 * 64];
    const int t = threadIdx.x;
    const int row0 = blockIdx.x * 128;
    const int tx = t & 15, ty = t >> 4;

    float acc[8][4] = {};

    for (int kk = 0; kk < K; kk += 64) {
        if (kk) __syncthreads();
        for (int i = t; i < 128 * 16; i += BLK) {
            int r = i >> 4, c = i & 15;
            int gr = row0 + r;
            float4 v = make_float4(0.f, 0.f, 0.f, 0.f);
            if (gr < M) {
                size_t ra = PIN ? ((size_t)(gr % B) * N + (gr / B)) : (size_t)gr;
                v = *reinterpret_cast<const float4*>(A + ra * K + kk + c * 4);
            }
            if (RELU) {
                v.x = fmaxf(v.x, 0.f); v.y = fmaxf(v.y, 0.f);
                v.z = fmaxf(v.z, 0.f); v.w = fmaxf(v.w, 0.f);
            }
            *reinterpret_cast<float4*>(As + r * 65 + c * 4) = v;
        }
        for (int i = t; i < 64 * 16; i += BLK) {
            int r = i >> 4, c = i & 15;
            *reinterpret_cast<float4*>(Bs + r * 64 + c * 4) =
                *reinterpret_cast<const float4*>(W + (size_t)(kk + r) * 64 + c * 4);
        }
        __syncthreads();

        #pragma unroll 4
        for (int k2 = 0; k2 < 64; ++k2) {
            float4 bv = *reinterpret_cast<const float4*>(Bs + k2 * 64 + tx * 4);
            float a[8];
            #pragma unroll
            for (int i = 0; i < 8; ++i) a[i] = As[(ty * 8 + i) * 65 + k2];
            #pragma unroll
            for (int i = 0; i < 8; ++i) {
                acc[i][0] = fmaf(a[i], bv.x, acc[i][0]);
                acc[i][1] = fmaf(a[i], bv.y, acc[i][1]);
                acc[i][2] = fmaf(a[i], bv.z, acc[i][2]);
                acc[i][3] = fmaf(a[i], bv.w, acc[i][3]);
            }
        }
    }

    #pragma unroll
    for (int i = 0; i < 8; ++i) {
        int gr = row0 + ty * 8 + i;
        if (gr < M) {
            float4 v = make_float4(acc[i][0], acc[i][1], acc[i][2], acc[i][3]);
            *reinterpret_cast<float4*>(C + (size_t)gr * 64 + tx * 4) = v;
        }
    }
}

// ---------------------------------------------------------------- gather aggregate
// Node-major [N][512] (B=8, H=64). One WAVE per dst node; lane l owns row
// float4s [l] and [l+64] (each edge = two fully-coalesced 1KB loads).
//   va -> b = lane>>4,     h = (lane&15)*4
//   vb -> b = 4+(lane>>4), h = (lane&15)*4
// FINAL: apply ReLU, dot with fcw, reduce per b, write 8 partials per block.
template <bool FINAL>
__global__ __launch_bounds__(BLK) void k_gather(const float* __restrict__ hw,
                                                const int* __restrict__ rs,
                                                const int* __restrict__ cnt,
                                                const int* __restrict__ csrc,
                                                const float* __restrict__ cw,
                                                const float* __restrict__ bias,
                                                float* __restrict__ agg,
                                                const float* __restrict__ fcw,
                                                float* __restrict__ partial, int N) {
    const int w = threadIdx.x >> 6, lane = threadIdx.x & 63;
    const int n = blockIdx.x * 4 + w;
    const bool active = (n < N);
    float4 a0 = make_float4(0.f, 0.f, 0.f, 0.f);
    float4 a1 = make_float4(0.f, 0.f, 0.f, 0.f);

    if (active) {
        const int beg = rs[n];
        const int deg = cnt[n];
        const float self = 1.0f / (1.0f + (float)deg);
        const float4* rowp = reinterpret_cast<const float4*>(hw + (size_t)n * 512);
        float4 v0 = rowp[lane], v1 = rowp[lane + 64];
        float4 bf = reinterpret_cast<const float4*>(bias)[lane & 15];
        a0.x = fmaf(v0.x, self, bf.x); a0.y = fmaf(v0.y, self, bf.y);
        a0.z = fmaf(v0.z, self, bf.z); a0.w = fmaf(v0.w, self, bf.w);
        a1.x = fmaf(v1.x, self, bf.x); a1.y = fmaf(v1.y, self, bf.y);
        a1.z = fmaf(v1.z, self, bf.z); a1.w = fmaf(v1.w, self, bf.w);

        int i = 0;
        for (; i + 2 <= deg; i += 2) {
            int s0 = csrc[beg + i], s1 = csrc[beg + i + 1];
            float w0 = cw[beg + i], w1 = cw[beg + i + 1];
            const float4* p0 = reinterpret_cast<const float4*>(hw + (size_t)s0 * 512);
            const float4* p1 = reinterpret_cast<const float4*>(hw + (size_t)s1 * 512);
            float4 x0 = p0[lane], y0 = p0[lane + 64];
            float4 x1 = p1[lane], y1 = p1[lane + 64];
            a0.x = fmaf(w0, x0.x, a0.x); a0.y = fmaf(w0, x0.y, a0.y);
            a0.z = fmaf(w0, x0.z, a0.z); a0.w = fmaf(w0, x0.w, a0.w);
            a1.x = fmaf(w0, y0.x, a1.x); a1.y = fmaf(w0, y0.y, a1.y);
            a1.z = fmaf(w0, y0.z, a1.z); a1.w = fmaf(w0, y0.w, a1.w);
            a0.x = fmaf(w1, x1.x, a0.x); a0.y = fmaf(w1, x1.y, a0.y);
            a0.z = fmaf(w1, x1.z, a0.z); a0.w = fmaf(w1, x1.w, a0.w);
            a1.x = fmaf(w1, y1.x, a1.x); a1.y = fmaf(w1, y1.y, a1.y);
            a1.z = fmaf(w1, y1.z, a1.z); a1.w = fmaf(w1, y1.w, a1.w);
        }
        if (i < deg) {
            int s0 = csrc[beg + i];
            float w0 = cw[beg + i];
            const float4* p0 = reinterpret_cast<const float4*>(hw + (size_t)s0 * 512);
            float4 x0 = p0[lane], y0 = p0[lane + 64];
            a0.x = fmaf(w0, x0.x, a0.x); a0.y = fmaf(w0, x0.y, a0.y);
            a0.z = fmaf(w0, x0.z, a0.z); a0.w = fmaf(w0, x0.w, a0.w);
            a1.x = fmaf(w0, y0.x, a1.x); a1.y = fmaf(w0, y0.y, a1.y);
            a1.z = fmaf(w0, y0.z, a1.z); a1.w = fmaf(w0, y0.w, a1.w);
        }
    }

    if (!FINAL) {
        if (active) {
            float4* op = reinterpret_cast<float4*>(agg + (size_t)n * 512);
            op[lane] = a0;
            op[lane + 64] = a1;
        }
    } else {
        __shared__ float sm[4][8];
        float4 fw = reinterpret_cast<const float4*>(fcw)[lane & 15];
        float s0 = fmaxf(a0.x, 0.f) * fw.x + fmaxf(a0.y, 0.f) * fw.y +
                   fmaxf(a0.z, 0.f) * fw.z + fmaxf(a0.w, 0.f) * fw.w;
        float s1 = fmaxf(a1.x, 0.f) * fw.x + fmaxf(a1.y, 0.f) * fw.y +
                   fmaxf(a1.z, 0.f) * fw.z + fmaxf(a1.w, 0.f) * fw.w;
        #pragma unroll
        for (int off = 1; off < 16; off <<= 1) {
            s0 += __shfl_xor(s0, off, 64);
            s1 += __shfl_xor(s1, off, 64);
        }
        if ((lane & 15) == 0) {
            sm[w][lane >> 4] = s0;
            sm[w][4 + (lane >> 4)] = s1;
        }
        __syncthreads();
        if (threadIdx.x < 8)
            partial[(size_t)blockIdx.x * 8 + threadIdx.x] =
                sm[0][threadIdx.x] + sm[1][threadIdx.x] + sm[2][threadIdx.x] + sm[3][threadIdx.x];
    }
}

// ---------------------------------------------------------------- finish
// out[b] = (sum over blocks of partial[blk][b]) / N + addf[b]*fcw[H] + fcb
__global__ void k_finish(const float* __restrict__ partial, int nblk,
                         const float* __restrict__ addf, const float* __restrict__ fcw,
                         const float* __restrict__ fcb, float* __restrict__ out,
                         int N, int H) {
    int b = blockIdx.x;
    float s = 0.f;
    for (int i = threadIdx.x; i < nblk; i += BLK) s += partial[(size_t)i * 8 + b];
    __shared__ float sm[BLK / 64];
    int lane = threadIdx.x & 63, w = threadIdx.x >> 6;
    #pragma unroll
    for (int off = 32; off; off >>= 1) s += __shfl_down(s, off, 64);
    if (lane == 0) sm[w] = s;
    __syncthreads();
    if (threadIdx.x == 0) {
        float t = sm[0] + sm[1] + sm[2] + sm[3];
        out[b] = t / (float)N + addf[b] * fcw[H] + fcb[0];
    }
}

// ---------------------------------------------------------------- launch
extern "C" void kernel_launch(void* const* d_in, const int* in_sizes, int n_in,
                              void* d_out, int out_size, void* d_ws, size_t ws_size,
                              hipStream_t stream) {
    const float* x    = (const float*)d_in[0];
    const float* addf = (const float*)d_in[1];
    const int*   ei   = (const int*)d_in[2];
    const float* W1   = (const float*)d_in[3];
    const float* b1   = (const float*)d_in[4];
    const float* W2   = (const float*)d_in[5];
    const float* b2   = (const float*)d_in[6];
    const float* fcw  = (const float*)d_in[7];
    const float* fcb  = (const float*)d_in[8];
    float* out = (float*)d_out;

    const int B  = in_sizes[1];            // 8
    const int H  = in_sizes[4];            // 64
    const int IN = in_sizes[3] / H;        // 128
    const int E  = in_sizes[2] / 2;        // 320000
    const int N  = in_sizes[0] / (B * IN); // 20000
    const int* src = ei;
    const int* dst = ei + E;

    const int M = B * N;                   // 160000 node-major rows

    float* ws = (float*)d_ws;
    size_t bufsz = (size_t)M * H;          // 10.24M floats
    float* bufA  = ws;                     // hw  [N][B*H]
    float* bufB  = ws + bufsz;             // agg [N][B*H]
    int*   cnt   = (int*)(bufB + bufsz);
    int*   rs    = cnt + N;
    int*   cur   = rs + N;
    int*   csrc  = cur + N;
    float* cw    = (float*)(csrc + E);
    int*   bsum  = (int*)(cw + E);
    float* partial = (float*)(bsum + 256);

    const int nbN = (N + BLK - 1) / BLK;
    const int nbE = (E + BLK - 1) / BLK;
    const int nodes4 = (N + 3) / 4;        // gather blocks (4 nodes/block)

    // CSR build
    k_zero<<<dim3(nbN), dim3(BLK), 0, stream>>>(cnt, N);
    k_count<<<dim3(nbE), dim3(BLK), 0, stream>>>(dst, cnt, E);
    k_scan1<<<dim3(nbN), dim3(BLK), 0, stream>>>(cnt, rs, bsum, N);
    k_scan2p<<<dim3(1), dim3(BLK), 0, stream>>>(bsum, nbN);
    k_scan3<<<dim3(nbN), dim3(BLK), 0, stream>>>(rs, cur, bsum, N);
    k_fill<<<dim3(nbE), dim3(BLK), 0, stream>>>(src, dst, cnt, cur, csrc, cw, E);

    // layer 1: hw1 = x @ W1 -> bufA (node-major out, batch-major in)
    k_gemm<128, false, true><<<dim3((M + 127) / 128), dim3(BLK), 0, stream>>>(
        x, W1, bufA, M, N, B);
    // agg1 = gather(hw1) + self + b1 -> bufB
    k_gather<false><<<dim3(nodes4), dim3(BLK), 0, stream>>>(
        bufA, rs, cnt, csrc, cw, b1, bufB, fcw, partial, N);

    // layer 2: hw2 = relu(agg1) @ W2 -> bufA
    k_gemm<64, true, false><<<dim3((M + 127) / 128), dim3(BLK), 0, stream>>>(
        bufB, W2, bufA, M, N, B);
    // layer-2 gather fused with ReLU + mean-pool + FC dot -> partials
    k_gather<true><<<dim3(nodes4), dim3(BLK), 0, stream>>>(
        bufA, rs, cnt, csrc, cw, b2, nullptr, fcw, partial, N);

    // final: sum partials, add additional_features term
    k_finish<<<dim3(B), dim3(BLK), 0, stream>>>(partial, nodes4, addf, fcw, fcb, out, N, H);
}

// Round 5
// 332.824 us; speedup vs baseline: 1.7127x; 1.3022x over previous
//
#include <hip/hip_runtime.h>

#define BLK 256

typedef __attribute__((ext_vector_type(8))) unsigned short ushort8v;

static __device__ __forceinline__ float bf2f(unsigned short u) {
    return __uint_as_float(((unsigned)u) << 16);
}
static __device__ __forceinline__ unsigned short f2bf(float f) {
    unsigned u = __float_as_uint(f);
    u += 0x7FFF + ((u >> 16) & 1);   // round-to-nearest-even
    return (unsigned short)(u >> 16);
}

// ---------------------------------------------------------------- zero
__global__ void k_zero(int* __restrict__ cnt, int N) {
    int i = blockIdx.x * BLK + threadIdx.x;
    if (i < N) cnt[i] = 0;
}

__global__ void k_count(const int* __restrict__ dst, int* __restrict__ cnt, int E) {
    int i = blockIdx.x * BLK + threadIdx.x;
    if (i < E) atomicAdd(&cnt[dst[i]], 1);
}

// ---------------------------------------------------------------- scan
__global__ void k_scan1(const int* __restrict__ cnt, int* __restrict__ rs,
                        int* __restrict__ bsum, int N) {
    __shared__ int s[BLK];
    int i = blockIdx.x * BLK + threadIdx.x;
    int v = (i < N) ? cnt[i] : 0;
    s[threadIdx.x] = v;
    __syncthreads();
    for (int off = 1; off < BLK; off <<= 1) {
        int t = (threadIdx.x >= off) ? s[threadIdx.x - off] : 0;
        __syncthreads();
        s[threadIdx.x] += t;
        __syncthreads();
    }
    if (i < N) rs[i] = s[threadIdx.x] - v;
    if (threadIdx.x == BLK - 1) bsum[blockIdx.x] = s[BLK - 1];
}

__global__ void k_scan2p(int* __restrict__ bsum, int nb) {
    __shared__ int s[BLK];
    int t = threadIdx.x;
    if (nb <= BLK) {
        int v = (t < nb) ? bsum[t] : 0;
        s[t] = v;
        __syncthreads();
        for (int off = 1; off < BLK; off <<= 1) {
            int u = (t >= off) ? s[t - off] : 0;
            __syncthreads();
            s[t] += u;
            __syncthreads();
        }
        if (t < nb) bsum[t] = s[t] - v;
    } else if (t == 0) {
        int r = 0;
        for (int i = 0; i < nb; ++i) { int x = bsum[i]; bsum[i] = r; r += x; }
    }
}

__global__ void k_scan3(int* __restrict__ rs, int* __restrict__ cur,
                        const int* __restrict__ bsum, int N) {
    int i = blockIdx.x * BLK + threadIdx.x;
    if (i < N) {
        int v = rs[i] + bsum[blockIdx.x];
        rs[i] = v;
        cur[i] = v;
    }
}

// ---------------------------------------------------------------- CSR fill
__global__ void k_fill(const int* __restrict__ src, const int* __restrict__ dst,
                       const int* __restrict__ cnt, int* __restrict__ cur,
                       int* __restrict__ csrc, float* __restrict__ cw, int E) {
    int e = blockIdx.x * BLK + threadIdx.x;
    if (e >= E) return;
    int d = dst[e], s = src[e];
    int p = atomicAdd(&cur[d], 1);
    csrc[p] = s;
    cw[p] = rsqrtf((1.0f + (float)cnt[s]) * (1.0f + (float)cnt[d]));
}

// ---------------------------------------------------------------- GEMM
// C[M][64](bf16) = op(A)[M][K] @ W[K][64](f32). 128-row tile, 256 threads,
// 8x4 register blocking, K staged in 64-chunks.
// ABF16: A is bf16 (GEMM2). PIN: x batch-major -> node-major rows (GEMM1).
template <int K, bool RELU, bool PIN, bool ABF16>
__global__ __launch_bounds__(BLK) void k_gemm(const void* __restrict__ Av,
                                              const float* __restrict__ W,
                                              unsigned short* __restrict__ C,
                                              int M, int N, int B) {
    __shared__ float As[128 * 65];
    __shared__ float Bs[64 * 64];
    const int t = threadIdx.x;
    const int row0 = blockIdx.x * 128;
    const int tx = t & 15, ty = t >> 4;

    float acc[8][4] = {};

    for (int kk = 0; kk < K; kk += 64) {
        if (kk) __syncthreads();
        if constexpr (!ABF16) {
            const float* A = (const float*)Av;
            for (int i = t; i < 128 * 16; i += BLK) {
                int r = i >> 4, c = i & 15;
                int gr = row0 + r;
                float4 v = make_float4(0.f, 0.f, 0.f, 0.f);
                if (gr < M) {
                    size_t ra = PIN ? ((size_t)(gr % B) * N + (gr / B)) : (size_t)gr;
                    v = *reinterpret_cast<const float4*>(A + ra * K + kk + c * 4);
                }
                if (RELU) {
                    v.x = fmaxf(v.x, 0.f); v.y = fmaxf(v.y, 0.f);
                    v.z = fmaxf(v.z, 0.f); v.w = fmaxf(v.w, 0.f);
                }
                *reinterpret_cast<float4*>(As + r * 65 + c * 4) = v;
            }
        } else {
            const unsigned short* A = (const unsigned short*)Av;
            for (int i = t; i < 128 * 8; i += BLK) {
                int r = i >> 3, c = i & 7;
                int gr = row0 + r;
                float f[8];
                if (gr < M) {
                    ushort8v v = *reinterpret_cast<const ushort8v*>(A + (size_t)gr * K + kk + c * 8);
                    #pragma unroll
                    for (int j = 0; j < 8; ++j) f[j] = bf2f(v[j]);
                } else {
                    #pragma unroll
                    for (int j = 0; j < 8; ++j) f[j] = 0.f;
                }
                if (RELU) {
                    #pragma unroll
                    for (int j = 0; j < 8; ++j) f[j] = fmaxf(f[j], 0.f);
                }
                float* dstp = As + r * 65 + c * 8;
                *reinterpret_cast<float4*>(dstp)     = make_float4(f[0], f[1], f[2], f[3]);
                *reinterpret_cast<float4*>(dstp + 4) = make_float4(f[4], f[5], f[6], f[7]);
            }
        }
        for (int i = t; i < 64 * 16; i += BLK) {
            int r = i >> 4, c = i & 15;
            *reinterpret_cast<float4*>(Bs + r * 64 + c * 4) =
                *reinterpret_cast<const float4*>(W + (size_t)(kk + r) * 64 + c * 4);
        }
        __syncthreads();

        #pragma unroll 4
        for (int k2 = 0; k2 < 64; ++k2) {
            float4 bv = *reinterpret_cast<const float4*>(Bs + k2 * 64 + tx * 4);
            float a[8];
            #pragma unroll
            for (int i = 0; i < 8; ++i) a[i] = As[(ty * 8 + i) * 65 + k2];
            #pragma unroll
            for (int i = 0; i < 8; ++i) {
                acc[i][0] = fmaf(a[i], bv.x, acc[i][0]);
                acc[i][1] = fmaf(a[i], bv.y, acc[i][1]);
                acc[i][2] = fmaf(a[i], bv.z, acc[i][2]);
                acc[i][3] = fmaf(a[i], bv.w, acc[i][3]);
            }
        }
    }

    #pragma unroll
    for (int i = 0; i < 8; ++i) {
        int gr = row0 + ty * 8 + i;
        if (gr < M) {
            ushort4 o;
            o.x = f2bf(acc[i][0]); o.y = f2bf(acc[i][1]);
            o.z = f2bf(acc[i][2]); o.w = f2bf(acc[i][3]);
            *reinterpret_cast<ushort4*>(C + (size_t)gr * 64 + tx * 4) = o;
        }
    }
}

// ---------------------------------------------------------------- gather aggregate
// hw: bf16 node-major [N][512] (B=8, H=64; row = 1KB). One WAVE per dst node;
// lane l owns channels [8l, 8l+8): b = l>>3, h = (l&7)*8 + j.
// One ushort8 load per edge per lane covers the whole row.
// FINAL: relu + dot fcw + per-b reduce (8-lane groups), 8 partials per block.
template <bool FINAL>
__global__ __launch_bounds__(BLK) void k_gather(const unsigned short* __restrict__ hw,
                                                const int* __restrict__ rs,
                                                const int* __restrict__ cnt,
                                                const int* __restrict__ csrc,
                                                const float* __restrict__ cw,
                                                const float* __restrict__ bias,
                                                unsigned short* __restrict__ agg,
                                                const float* __restrict__ fcw,
                                                float* __restrict__ partial, int N) {
    const int w = threadIdx.x >> 6, lane = threadIdx.x & 63;
    const int n = blockIdx.x * 4 + w;
    const bool active = (n < N);
    float a[8] = {};

    if (active) {
        const int beg = rs[n];
        const int deg = cnt[n];
        const float self = 1.0f / (1.0f + (float)deg);
        // bias for channels (lane&7)*8 .. +8
        const float* bp = bias + (lane & 7) * 8;
        ushort8v v = *reinterpret_cast<const ushort8v*>(hw + (size_t)n * 512 + lane * 8);
        #pragma unroll
        for (int j = 0; j < 8; ++j) a[j] = fmaf(bf2f(v[j]), self, bp[j]);

        int i = 0;
        for (; i + 2 <= deg; i += 2) {
            int s0 = csrc[beg + i], s1 = csrc[beg + i + 1];
            float w0 = cw[beg + i], w1 = cw[beg + i + 1];
            ushort8v x0 = *reinterpret_cast<const ushort8v*>(hw + (size_t)s0 * 512 + lane * 8);
            ushort8v x1 = *reinterpret_cast<const ushort8v*>(hw + (size_t)s1 * 512 + lane * 8);
            #pragma unroll
            for (int j = 0; j < 8; ++j) a[j] = fmaf(w0, bf2f(x0[j]), a[j]);
            #pragma unroll
            for (int j = 0; j < 8; ++j) a[j] = fmaf(w1, bf2f(x1[j]), a[j]);
        }
        if (i < deg) {
            int s0 = csrc[beg + i];
            float w0 = cw[beg + i];
            ushort8v x0 = *reinterpret_cast<const ushort8v*>(hw + (size_t)s0 * 512 + lane * 8);
            #pragma unroll
            for (int j = 0; j < 8; ++j) a[j] = fmaf(w0, bf2f(x0[j]), a[j]);
        }
    }

    if (!FINAL) {
        if (active) {
            ushort8v o;
            #pragma unroll
            for (int j = 0; j < 8; ++j) o[j] = f2bf(a[j]);
            *reinterpret_cast<ushort8v*>(agg + (size_t)n * 512 + lane * 8) = o;
        }
    } else {
        __shared__ float sm[4][8];
        const float* fp = fcw + (lane & 7) * 8;
        float s = 0.f;
        #pragma unroll
        for (int j = 0; j < 8; ++j) s = fmaf(fmaxf(a[j], 0.f), fp[j], s);
        // reduce within 8-lane group (same b = lane>>3)
        #pragma unroll
        for (int off = 1; off < 8; off <<= 1) s += __shfl_xor(s, off, 64);
        if ((lane & 7) == 0) sm[w][lane >> 3] = s;
        __syncthreads();
        if (threadIdx.x < 8)
            partial[(size_t)blockIdx.x * 8 + threadIdx.x] =
                sm[0][threadIdx.x] + sm[1][threadIdx.x] + sm[2][threadIdx.x] + sm[3][threadIdx.x];
    }
}

// ---------------------------------------------------------------- finish
__global__ void k_finish(const float* __restrict__ partial, int nblk,
                         const float* __restrict__ addf, const float* __restrict__ fcw,
                         const float* __restrict__ fcb, float* __restrict__ out,
                         int N, int H) {
    int b = blockIdx.x;
    float s = 0.f;
    for (int i = threadIdx.x; i < nblk; i += BLK) s += partial[(size_t)i * 8 + b];
    __shared__ float sm[BLK / 64];
    int lane = threadIdx.x & 63, w = threadIdx.x >> 6;
    #pragma unroll
    for (int off = 32; off; off >>= 1) s += __shfl_down(s, off, 64);
    if (lane == 0) sm[w] = s;
    __syncthreads();
    if (threadIdx.x == 0) {
        float t = sm[0] + sm[1] + sm[2] + sm[3];
        out[b] = t / (float)N + addf[b] * fcw[H] + fcb[0];
    }
}

// ---------------------------------------------------------------- launch
extern "C" void kernel_launch(void* const* d_in, const int* in_sizes, int n_in,
                              void* d_out, int out_size, void* d_ws, size_t ws_size,
                              hipStream_t stream) {
    const float* x    = (const float*)d_in[0];
    const float* addf = (const float*)d_in[1];
    const int*   ei   = (const int*)d_in[2];
    const float* W1   = (const float*)d_in[3];
    const float* b1   = (const float*)d_in[4];
    const float* W2   = (const float*)d_in[5];
    const float* b2   = (const float*)d_in[6];
    const float* fcw  = (const float*)d_in[7];
    const float* fcb  = (const float*)d_in[8];
    float* out = (float*)d_out;

    const int B  = in_sizes[1];            // 8
    const int H  = in_sizes[4];            // 64
    const int IN = in_sizes[3] / H;        // 128
    const int E  = in_sizes[2] / 2;        // 320000
    const int N  = in_sizes[0] / (B * IN); // 20000
    const int* src = ei;
    const int* dst = ei + E;

    const int M = B * N;                   // 160000 node-major rows

    size_t bufsz = (size_t)M * H;          // elements per hw/agg buffer
    unsigned short* bufA = (unsigned short*)d_ws;      // hw  [N][512] bf16
    unsigned short* bufB = bufA + bufsz;               // agg [N][512] bf16
    int*   cnt   = (int*)(bufB + bufsz);
    int*   rs    = cnt + N;
    int*   cur   = rs + N;
    int*   csrc  = cur + N;
    float* cw    = (float*)(csrc + E);
    int*   bsum  = (int*)(cw + E);
    float* partial = (float*)(bsum + 256);

    const int nbN = (N + BLK - 1) / BLK;
    const int nbE = (E + BLK - 1) / BLK;
    const int nodes4 = (N + 3) / 4;

    // CSR build
    k_zero<<<dim3(nbN), dim3(BLK), 0, stream>>>(cnt, N);
    k_count<<<dim3(nbE), dim3(BLK), 0, stream>>>(dst, cnt, E);
    k_scan1<<<dim3(nbN), dim3(BLK), 0, stream>>>(cnt, rs, bsum, N);
    k_scan2p<<<dim3(1), dim3(BLK), 0, stream>>>(bsum, nbN);
    k_scan3<<<dim3(nbN), dim3(BLK), 0, stream>>>(rs, cur, bsum, N);
    k_fill<<<dim3(nbE), dim3(BLK), 0, stream>>>(src, dst, cnt, cur, csrc, cw, E);

    // layer 1: hw1 = x @ W1 -> bufA (bf16, node-major)
    k_gemm<128, false, true, false><<<dim3((M + 127) / 128), dim3(BLK), 0, stream>>>(
        x, W1, bufA, M, N, B);
    // agg1 = gather(hw1) + self + b1 -> bufB (bf16)
    k_gather<false><<<dim3(nodes4), dim3(BLK), 0, stream>>>(
        bufA, rs, cnt, csrc, cw, b1, bufB, fcw, partial, N);

    // layer 2: hw2 = relu(agg1) @ W2 -> bufA (bf16)
    k_gemm<64, true, false, true><<<dim3((M + 127) / 128), dim3(BLK), 0, stream>>>(
        bufB, W2, bufA, M, N, B);
    // layer-2 gather fused with ReLU + mean-pool + FC dot -> partials
    k_gather<true><<<dim3(nodes4), dim3(BLK), 0, stream>>>(
        bufA, rs, cnt, csrc, cw, b2, nullptr, fcw, partial, N);

    // final
    k_finish<<<dim3(B), dim3(BLK), 0, stream>>>(partial, nodes4, addf, fcw, fcb, out, N, H);
}

// Round 6
// 325.377 us; speedup vs baseline: 1.7519x; 1.0229x over previous
//
#include <hip/hip_runtime.h>

#define BLK 256

typedef __attribute__((ext_vector_type(8))) unsigned short ushort8v;
typedef __attribute__((ext_vector_type(4))) unsigned short ushort4v;
typedef __attribute__((ext_vector_type(8))) short short8v;   // bf16x8 MFMA frag
typedef __attribute__((ext_vector_type(4))) float f32x4;     // MFMA acc

static __device__ __forceinline__ float bf2f(unsigned short u) {
    return __uint_as_float(((unsigned)u) << 16);
}
static __device__ __forceinline__ unsigned short f2bf(float f) {
    unsigned u = __float_as_uint(f);
    u += 0x7FFF + ((u >> 16) & 1);   // RNE
    return (unsigned short)(u >> 16);
}

// ---------------------------------------------------------------- init: zero cnt + W->bf16^T
__global__ void k_init(int* __restrict__ cnt, int N,
                       const float* __restrict__ W1, const float* __restrict__ W2,
                       unsigned short* __restrict__ Wt1, unsigned short* __restrict__ Wt2,
                       int IN, int H) {
    int i = blockIdx.x * BLK + threadIdx.x;
    if (i < N) cnt[i] = 0;
    if (i < IN * H) {                 // Wt1[c][k] = bf16(W1[k][c])
        int k = i / H, c = i % H;
        Wt1[(size_t)c * IN + k] = f2bf(W1[i]);
    }
    if (i < H * H) {
        int k = i / H, c = i % H;
        Wt2[(size_t)c * H + k] = f2bf(W2[i]);
    }
}

__global__ void k_count(const int* __restrict__ dst, int* __restrict__ cnt, int E) {
    int i = blockIdx.x * BLK + threadIdx.x;
    if (i < E) atomicAdd(&cnt[dst[i]], 1);
}

// ---------------------------------------------------------------- single-block scan
__global__ __launch_bounds__(1024) void k_scan_all(const int* __restrict__ cnt,
                                                   int* __restrict__ rs,
                                                   int* __restrict__ cur, int N) {
    __shared__ int sm[1024];
    const int t = threadIdx.x;
    const int chunk = (N + 1023) >> 10;
    const int lo = t * chunk;
    const int hi = min(lo + chunk, N);
    int s = 0;
    for (int i = lo; i < hi; ++i) s += cnt[i];
    sm[t] = s;
    __syncthreads();
    for (int off = 1; off < 1024; off <<= 1) {
        int v = (t >= off) ? sm[t - off] : 0;
        __syncthreads();
        sm[t] += v;
        __syncthreads();
    }
    int run = sm[t] - s;   // exclusive prefix for this chunk
    for (int i = lo; i < hi; ++i) {
        int c = cnt[i];
        rs[i] = run; cur[i] = run;
        run += c;
    }
}

// ---------------------------------------------------------------- CSR fill
__global__ void k_fill(const int* __restrict__ src, const int* __restrict__ dst,
                       const int* __restrict__ cnt, int* __restrict__ cur,
                       int* __restrict__ csrc, float* __restrict__ cw, int E) {
    int e = blockIdx.x * BLK + threadIdx.x;
    if (e >= E) return;
    int d = dst[e], s = src[e];
    int p = atomicAdd(&cur[d], 1);
    csrc[p] = s;
    cw[p] = rsqrtf((1.0f + (float)cnt[s]) * (1.0f + (float)cnt[d]));
}

// ---------------------------------------------------------------- MFMA GEMM
// C[M][64](bf16) = op(A)[M][K] @ W[K][64], W given as Wt bf16 [64][K].
// 128-row tile, 256 thr = 4 waves; wave w: rows w*32..+31 (2 frags) x 64 cols (4 frags).
// mfma_f32_16x16x32_bf16: A[l&15][(l>>4)*8+j], B[(l>>4)*8+j][l&15], D col=l&15,row=(l>>4)*4+reg.
template <int K, bool RELU, bool PIN, bool ABF16>
__global__ __launch_bounds__(BLK) void k_gemm_mfma(const void* __restrict__ Av,
                                                   const unsigned short* __restrict__ Wt,
                                                   unsigned short* __restrict__ C,
                                                   int M, int N, int B) {
    constexpr int LDA = K + 8;               // ushort stride: 272B/144B rows -> bank rotate 4
    __shared__ unsigned short As[128 * LDA];
    __shared__ unsigned short Bs[64 * LDA];
    const int t = threadIdx.x;
    const int row0 = blockIdx.x * 128;

    // stage Wt[64][K] -> Bs
    for (int i = t; i < 64 * (K / 8); i += BLK) {
        int r = i / (K / 8), c = i % (K / 8);
        *reinterpret_cast<ushort8v*>(&Bs[r * LDA + c * 8]) =
            *reinterpret_cast<const ushort8v*>(Wt + (size_t)r * K + c * 8);
    }
    // stage A -> As (bf16)
    if constexpr (!ABF16) {
        const float* A = (const float*)Av;
        for (int i = t; i < 128 * (K / 4); i += BLK) {
            int r = i / (K / 4), c = i % (K / 4);
            int gr = row0 + r;
            float4 v = make_float4(0.f, 0.f, 0.f, 0.f);
            if (gr < M) {
                size_t ra = PIN ? ((size_t)(gr % B) * N + (gr / B)) : (size_t)gr;
                v = *reinterpret_cast<const float4*>(A + ra * K + c * 4);
            }
            if (RELU) {
                v.x = fmaxf(v.x, 0.f); v.y = fmaxf(v.y, 0.f);
                v.z = fmaxf(v.z, 0.f); v.w = fmaxf(v.w, 0.f);
            }
            ushort4v o;
            o[0] = f2bf(v.x); o[1] = f2bf(v.y); o[2] = f2bf(v.z); o[3] = f2bf(v.w);
            *reinterpret_cast<ushort4v*>(&As[r * LDA + c * 4]) = o;
        }
    } else {
        const unsigned short* A = (const unsigned short*)Av;
        for (int i = t; i < 128 * (K / 8); i += BLK) {
            int r = i / (K / 8), c = i % (K / 8);
            int gr = row0 + r;
            ushort8v v = {0, 0, 0, 0, 0, 0, 0, 0};
            if (gr < M) v = *reinterpret_cast<const ushort8v*>(A + (size_t)gr * K + c * 8);
            if (RELU) {
                #pragma unroll
                for (int j = 0; j < 8; ++j) v[j] = (v[j] & 0x8000) ? 0 : v[j];
            }
            *reinterpret_cast<ushort8v*>(&As[r * LDA + c * 8]) = v;
        }
    }
    __syncthreads();

    const int w = t >> 6, lane = t & 63;
    const int lrow = lane & 15;
    const int lk = (lane >> 4) * 8;

    f32x4 acc[2][4] = {};
    #pragma unroll
    for (int ks = 0; ks < K / 32; ++ks) {
        short8v a[2], b[4];
        #pragma unroll
        for (int fr = 0; fr < 2; ++fr)
            a[fr] = *reinterpret_cast<const short8v*>(
                &As[(w * 32 + fr * 16 + lrow) * LDA + ks * 32 + lk]);
        #pragma unroll
        for (int fc = 0; fc < 4; ++fc)
            b[fc] = *reinterpret_cast<const short8v*>(
                &Bs[(fc * 16 + lrow) * LDA + ks * 32 + lk]);
        #pragma unroll
        for (int fr = 0; fr < 2; ++fr)
            #pragma unroll
            for (int fc = 0; fc < 4; ++fc)
                acc[fr][fc] = __builtin_amdgcn_mfma_f32_16x16x32_bf16(
                    a[fr], b[fc], acc[fr][fc], 0, 0, 0);
    }

    // epilogue: repack via LDS (stride 72 ushort = 144B, 16B-aligned rows)
    __syncthreads();
    #pragma unroll
    for (int fr = 0; fr < 2; ++fr)
        #pragma unroll
        for (int fc = 0; fc < 4; ++fc)
            #pragma unroll
            for (int j = 0; j < 4; ++j)
                As[(w * 32 + fr * 16 + (lane >> 4) * 4 + j) * 72 + fc * 16 + lrow] =
                    f2bf(acc[fr][fc][j]);
    __syncthreads();
    for (int i = t; i < 128 * 8; i += BLK) {
        int r = i >> 3, c = i & 7;
        int gr = row0 + r;
        if (gr < M)
            *reinterpret_cast<ushort8v*>(C + (size_t)gr * 64 + c * 8) =
                *reinterpret_cast<const ushort8v*>(&As[r * 72 + c * 8]);
    }
}

// ---------------------------------------------------------------- gather aggregate
// hw: bf16 node-major [N][512] (B=8, H=64; row = 1KB). One WAVE per dst node;
// lane l owns channels [8l, 8l+8): b = l>>3, h = (l&7)*8 + j.
template <bool FINAL>
__global__ __launch_bounds__(BLK) void k_gather(const unsigned short* __restrict__ hw,
                                                const int* __restrict__ rs,
                                                const int* __restrict__ cnt,
                                                const int* __restrict__ csrc,
                                                const float* __restrict__ cw,
                                                const float* __restrict__ bias,
                                                unsigned short* __restrict__ agg,
                                                const float* __restrict__ fcw,
                                                float* __restrict__ partial, int N) {
    const int w = threadIdx.x >> 6, lane = threadIdx.x & 63;
    const int n = blockIdx.x * 4 + w;
    const bool active = (n < N);
    float a[8] = {};

    if (active) {
        const int beg = rs[n];
        const int deg = cnt[n];
        const float self = 1.0f / (1.0f + (float)deg);
        const float* bp = bias + (lane & 7) * 8;
        ushort8v v = *reinterpret_cast<const ushort8v*>(hw + (size_t)n * 512 + lane * 8);
        #pragma unroll
        for (int j = 0; j < 8; ++j) a[j] = fmaf(bf2f(v[j]), self, bp[j]);

        int i = 0;
        for (; i + 2 <= deg; i += 2) {
            int s0 = csrc[beg + i], s1 = csrc[beg + i + 1];
            float w0 = cw[beg + i], w1 = cw[beg + i + 1];
            ushort8v x0 = *reinterpret_cast<const ushort8v*>(hw + (size_t)s0 * 512 + lane * 8);
            ushort8v x1 = *reinterpret_cast<const ushort8v*>(hw + (size_t)s1 * 512 + lane * 8);
            #pragma unroll
            for (int j = 0; j < 8; ++j) a[j] = fmaf(w0, bf2f(x0[j]), a[j]);
            #pragma unroll
            for (int j = 0; j < 8; ++j) a[j] = fmaf(w1, bf2f(x1[j]), a[j]);
        }
        if (i < deg) {
            int s0 = csrc[beg + i];
            float w0 = cw[beg + i];
            ushort8v x0 = *reinterpret_cast<const ushort8v*>(hw + (size_t)s0 * 512 + lane * 8);
            #pragma unroll
            for (int j = 0; j < 8; ++j) a[j] = fmaf(w0, bf2f(x0[j]), a[j]);
        }
    }

    if (!FINAL) {
        if (active) {
            ushort8v o;
            #pragma unroll
            for (int j = 0; j < 8; ++j) o[j] = f2bf(a[j]);
            *reinterpret_cast<ushort8v*>(agg + (size_t)n * 512 + lane * 8) = o;
        }
    } else {
        __shared__ float sm[4][8];
        const float* fp = fcw + (lane & 7) * 8;
        float s = 0.f;
        #pragma unroll
        for (int j = 0; j < 8; ++j) s = fmaf(fmaxf(a[j], 0.f), fp[j], s);
        #pragma unroll
        for (int off = 1; off < 8; off <<= 1) s += __shfl_xor(s, off, 64);
        if ((lane & 7) == 0) sm[w][lane >> 3] = s;
        __syncthreads();
        if (threadIdx.x < 8)
            partial[(size_t)blockIdx.x * 8 + threadIdx.x] =
                sm[0][threadIdx.x] + sm[1][threadIdx.x] + sm[2][threadIdx.x] + sm[3][threadIdx.x];
    }
}

// ---------------------------------------------------------------- finish
__global__ void k_finish(const float* __restrict__ partial, int nblk,
                         const float* __restrict__ addf, const float* __restrict__ fcw,
                         const float* __restrict__ fcb, float* __restrict__ out,
                         int N, int H) {
    int b = blockIdx.x;
    float s = 0.f;
    for (int i = threadIdx.x; i < nblk; i += BLK) s += partial[(size_t)i * 8 + b];
    __shared__ float sm[BLK / 64];
    int lane = threadIdx.x & 63, w = threadIdx.x >> 6;
    #pragma unroll
    for (int off = 32; off; off >>= 1) s += __shfl_down(s, off, 64);
    if (lane == 0) sm[w] = s;
    __syncthreads();
    if (threadIdx.x == 0) {
        float t = sm[0] + sm[1] + sm[2] + sm[3];
        out[b] = t / (float)N + addf[b] * fcw[H] + fcb[0];
    }
}

// ---------------------------------------------------------------- launch
extern "C" void kernel_launch(void* const* d_in, const int* in_sizes, int n_in,
                              void* d_out, int out_size, void* d_ws, size_t ws_size,
                              hipStream_t stream) {
    const float* x    = (const float*)d_in[0];
    const float* addf = (const float*)d_in[1];
    const int*   ei   = (const int*)d_in[2];
    const float* W1   = (const float*)d_in[3];
    const float* b1   = (const float*)d_in[4];
    const float* W2   = (const float*)d_in[5];
    const float* b2   = (const float*)d_in[6];
    const float* fcw  = (const float*)d_in[7];
    const float* fcb  = (const float*)d_in[8];
    float* out = (float*)d_out;

    const int B  = in_sizes[1];            // 8
    const int H  = in_sizes[4];            // 64
    const int IN = in_sizes[3] / H;        // 128
    const int E  = in_sizes[2] / 2;        // 320000
    const int N  = in_sizes[0] / (B * IN); // 20000
    const int* src = ei;
    const int* dst = ei + E;

    const int M = B * N;                   // 160000 node-major rows

    size_t bufsz = (size_t)M * H;
    unsigned short* bufA = (unsigned short*)d_ws;      // hw  [N][512] bf16
    unsigned short* bufB = bufA + bufsz;               // agg [N][512] bf16
    int*   cnt   = (int*)(bufB + bufsz);
    int*   rs    = cnt + N;
    int*   cur   = rs + N;
    int*   csrc  = cur + N;
    float* cw    = (float*)(csrc + E);
    unsigned short* Wt1 = (unsigned short*)(cw + E);   // [64][128] bf16
    unsigned short* Wt2 = Wt1 + (size_t)H * IN;        // [64][64] bf16
    float* partial = (float*)(Wt2 + (size_t)H * H);

    const int nbN = (N + BLK - 1) / BLK;
    const int nbE = (E + BLK - 1) / BLK;
    const int nodes4 = (N + 3) / 4;

    // CSR build + weight conversion
    k_init<<<dim3(nbN), dim3(BLK), 0, stream>>>(cnt, N, W1, W2, Wt1, Wt2, IN, H);
    k_count<<<dim3(nbE), dim3(BLK), 0, stream>>>(dst, cnt, E);
    k_scan_all<<<dim3(1), dim3(1024), 0, stream>>>(cnt, rs, cur, N);
    k_fill<<<dim3(nbE), dim3(BLK), 0, stream>>>(src, dst, cnt, cur, csrc, cw, E);

    // layer 1: hw1 = bf16(x) @ bf16(W1) -> bufA (node-major)
    k_gemm_mfma<128, false, true, false><<<dim3((M + 127) / 128), dim3(BLK), 0, stream>>>(
        x, Wt1, bufA, M, N, B);
    // agg1 = gather(hw1) + self + b1 -> bufB
    k_gather<false><<<dim3(nodes4), dim3(BLK), 0, stream>>>(
        bufA, rs, cnt, csrc, cw, b1, bufB, fcw, partial, N);

    // layer 2: hw2 = relu(agg1) @ bf16(W2) -> bufA
    k_gemm_mfma<64, true, false, true><<<dim3((M + 127) / 128), dim3(BLK), 0, stream>>>(
        bufB, Wt2, bufA, M, N, B);
    // layer-2 gather fused with ReLU + mean-pool + FC dot -> partials
    k_gather<true><<<dim3(nodes4), dim3(BLK), 0, stream>>>(
        bufA, rs, cnt, csrc, cw, b2, nullptr, fcw, partial, N);

    // final
    k_finish<<<dim3(B), dim3(BLK), 0, stream>>>(partial, nodes4, addf, fcw, fcb, out, N, H);
}

// Round 7
// 314.412 us; speedup vs baseline: 1.8130x; 1.0349x over previous
//
#include <hip/hip_runtime.h>

#define BLK 256

typedef __attribute__((ext_vector_type(8))) unsigned short ushort8v;
typedef __attribute__((ext_vector_type(4))) unsigned short ushort4v;
typedef __attribute__((ext_vector_type(8))) short short8v;   // bf16x8 MFMA frag
typedef __attribute__((ext_vector_type(4))) float f32x4;     // MFMA acc

static __device__ __forceinline__ float bf2f(unsigned short u) {
    return __uint_as_float(((unsigned)u) << 16);
}
static __device__ __forceinline__ unsigned short f2bf(float f) {
    unsigned u = __float_as_uint(f);
    u += 0x7FFF + ((u >> 16) & 1);   // RNE
    return (unsigned short)(u >> 16);
}

// ---------------------------------------------------------------- init: zero cnt + W->bf16^T
__global__ void k_init(int* __restrict__ cnt, int N,
                       const float* __restrict__ W1, const float* __restrict__ W2,
                       unsigned short* __restrict__ Wt1, unsigned short* __restrict__ Wt2,
                       int IN, int H) {
    int i = blockIdx.x * BLK + threadIdx.x;
    if (i < N) cnt[i] = 0;
    if (i < IN * H) {                 // Wt1[c][k] = bf16(W1[k][c])
        int k = i / H, c = i % H;
        Wt1[(size_t)c * IN + k] = f2bf(W1[i]);
    }
    if (i < H * H) {
        int k = i / H, c = i % H;
        Wt2[(size_t)c * H + k] = f2bf(W2[i]);
    }
}

__global__ void k_count(const int* __restrict__ dst, int* __restrict__ cnt, int E) {
    int i = blockIdx.x * BLK + threadIdx.x;
    if (i < E) atomicAdd(&cnt[dst[i]], 1);
}

// ---------------------------------------------------------------- single-block scan
__global__ __launch_bounds__(1024) void k_scan_all(const int* __restrict__ cnt,
                                                   int* __restrict__ rs,
                                                   int* __restrict__ cur, int N) {
    __shared__ int sm[1024];
    const int t = threadIdx.x;
    const int chunk = (N + 1023) >> 10;
    const int lo = t * chunk;
    const int hi = min(lo + chunk, N);
    int s = 0;
    for (int i = lo; i < hi; ++i) s += cnt[i];
    sm[t] = s;
    __syncthreads();
    for (int off = 1; off < 1024; off <<= 1) {
        int v = (t >= off) ? sm[t - off] : 0;
        __syncthreads();
        sm[t] += v;
        __syncthreads();
    }
    int run = sm[t] - s;
    for (int i = lo; i < hi; ++i) {
        int c = cnt[i];
        rs[i] = run; cur[i] = run;
        run += c;
    }
}

// ---------------------------------------------------------------- CSR fill
__global__ void k_fill(const int* __restrict__ src, const int* __restrict__ dst,
                       const int* __restrict__ cnt, int* __restrict__ cur,
                       int* __restrict__ csrc, float* __restrict__ cw, int E) {
    int e = blockIdx.x * BLK + threadIdx.x;
    if (e >= E) return;
    int d = dst[e], s = src[e];
    int p = atomicAdd(&cur[d], 1);
    csrc[p] = s;
    cw[p] = rsqrtf((1.0f + (float)cnt[s]) * (1.0f + (float)cnt[d]));
}

// ---------------------------------------------------------------- MFMA GEMM (layer 1)
// C[M][64](bf16) = bf16(x)[M][128] @ W1, Wt bf16 [64][128]. 128-row tile, 4 waves.
template <int K>
__global__ __launch_bounds__(BLK) void k_gemm_mfma(const float* __restrict__ A,
                                                   const unsigned short* __restrict__ Wt,
                                                   unsigned short* __restrict__ C,
                                                   int M, int N, int B) {
    constexpr int LDA = K + 8;
    __shared__ unsigned short As[128 * LDA];
    __shared__ unsigned short Bs[64 * LDA];
    const int t = threadIdx.x;
    const int row0 = blockIdx.x * 128;

    for (int i = t; i < 64 * (K / 8); i += BLK) {
        int r = i / (K / 8), c = i % (K / 8);
        *reinterpret_cast<ushort8v*>(&Bs[r * LDA + c * 8]) =
            *reinterpret_cast<const ushort8v*>(Wt + (size_t)r * K + c * 8);
    }
    for (int i = t; i < 128 * (K / 4); i += BLK) {
        int r = i / (K / 4), c = i % (K / 4);
        int gr = row0 + r;
        float4 v = make_float4(0.f, 0.f, 0.f, 0.f);
        if (gr < M) {
            size_t ra = (size_t)(gr % B) * N + (gr / B);   // x batch-major -> node-major
            v = *reinterpret_cast<const float4*>(A + ra * K + c * 4);
        }
        ushort4v o;
        o[0] = f2bf(v.x); o[1] = f2bf(v.y); o[2] = f2bf(v.z); o[3] = f2bf(v.w);
        *reinterpret_cast<ushort4v*>(&As[r * LDA + c * 4]) = o;
    }
    __syncthreads();

    const int w = t >> 6, lane = t & 63;
    const int lrow = lane & 15;
    const int lk = (lane >> 4) * 8;

    f32x4 acc[2][4] = {};
    #pragma unroll
    for (int ks = 0; ks < K / 32; ++ks) {
        short8v a[2], b[4];
        #pragma unroll
        for (int fr = 0; fr < 2; ++fr)
            a[fr] = *reinterpret_cast<const short8v*>(
                &As[(w * 32 + fr * 16 + lrow) * LDA + ks * 32 + lk]);
        #pragma unroll
        for (int fc = 0; fc < 4; ++fc)
            b[fc] = *reinterpret_cast<const short8v*>(
                &Bs[(fc * 16 + lrow) * LDA + ks * 32 + lk]);
        #pragma unroll
        for (int fr = 0; fr < 2; ++fr)
            #pragma unroll
            for (int fc = 0; fc < 4; ++fc)
                acc[fr][fc] = __builtin_amdgcn_mfma_f32_16x16x32_bf16(
                    a[fr], b[fc], acc[fr][fc], 0, 0, 0);
    }

    __syncthreads();
    #pragma unroll
    for (int fr = 0; fr < 2; ++fr)
        #pragma unroll
        for (int fc = 0; fc < 4; ++fc)
            #pragma unroll
            for (int j = 0; j < 4; ++j)
                As[(w * 32 + fr * 16 + (lane >> 4) * 4 + j) * 72 + fc * 16 + lrow] =
                    f2bf(acc[fr][fc][j]);
    __syncthreads();
    for (int i = t; i < 128 * 8; i += BLK) {
        int r = i >> 3, c = i & 7;
        int gr = row0 + r;
        if (gr < M)
            *reinterpret_cast<ushort8v*>(C + (size_t)gr * 64 + c * 8) =
                *reinterpret_cast<const ushort8v*>(&As[r * 72 + c * 8]);
    }
}

// ---------------------------------------------------------------- edge accumulate helpers
#define EDGE_ACC(S, W)                                                              \
    {                                                                               \
        ushort8v _x = *reinterpret_cast<const ushort8v*>(                           \
            hw + (size_t)(S) * 512 + lane * 8);                                     \
        _Pragma("unroll")                                                           \
        for (int j = 0; j < 8; ++j) a[j] = fmaf((W), bf2f(_x[j]), a[j]);            \
    }

// ---------------------------------------------------------------- fused gather1 + GEMM2
// Block = 4 dst nodes (1 wave each). Gather agg1 rows (f32 in regs), relu -> bf16
// tile [32 rows=(node,b)][64 h], then tile @ W2 via MFMA, store hw2 [N][512] bf16.
__global__ __launch_bounds__(BLK) void k_gather_gemm(const unsigned short* __restrict__ hw,
                                                     const int* __restrict__ rs,
                                                     const int* __restrict__ cnt,
                                                     const int* __restrict__ csrc,
                                                     const float* __restrict__ cw,
                                                     const float* __restrict__ bias,
                                                     const unsigned short* __restrict__ Wt2,
                                                     unsigned short* __restrict__ hw2,
                                                     int N) {
    __shared__ unsigned short Ws[64 * 72];    // Wt2 staged
    __shared__ unsigned short Tile[32 * 72];  // relu(agg1) tile, then D repack
    const int t = threadIdx.x;
    const int wv = t >> 6, lane = t & 63;
    const int n = blockIdx.x * 4 + wv;

    for (int i = t; i < 64 * 8; i += BLK) {
        int r = i >> 3, c = i & 7;
        *reinterpret_cast<ushort8v*>(&Ws[r * 72 + c * 8]) =
            *reinterpret_cast<const ushort8v*>(Wt2 + (size_t)r * 64 + c * 8);
    }

    float a[8];
    {
        const int beg = rs[n];
        const int deg = cnt[n];
        const float self = 1.0f / (1.0f + (float)deg);
        const float* bp = bias + (lane & 7) * 8;
        ushort8v v = *reinterpret_cast<const ushort8v*>(hw + (size_t)n * 512 + lane * 8);
        #pragma unroll
        for (int j = 0; j < 8; ++j) a[j] = fmaf(bf2f(v[j]), self, bp[j]);

        int i = 0;
        for (; i + 4 <= deg; i += 4) {
            int s0 = csrc[beg + i],     s1 = csrc[beg + i + 1];
            int s2 = csrc[beg + i + 2], s3 = csrc[beg + i + 3];
            float w0 = cw[beg + i],     w1 = cw[beg + i + 1];
            float w2 = cw[beg + i + 2], w3 = cw[beg + i + 3];
            EDGE_ACC(s0, w0); EDGE_ACC(s1, w1); EDGE_ACC(s2, w2); EDGE_ACC(s3, w3);
        }
        for (; i < deg; ++i) {
            int s0 = csrc[beg + i];
            float w0 = cw[beg + i];
            EDGE_ACC(s0, w0);
        }
    }
    {
        ushort8v o;
        #pragma unroll
        for (int j = 0; j < 8; ++j) o[j] = f2bf(fmaxf(a[j], 0.f));
        *reinterpret_cast<ushort8v*>(&Tile[(wv * 8 + (lane >> 3)) * 72 + (lane & 7) * 8]) = o;
    }
    __syncthreads();

    // MFMA: wave wv -> rows r0=(wv>>1)*16, cols c0=(wv&1)*32
    const int lrow = lane & 15, lk = (lane >> 4) * 8;
    const int r0 = (wv >> 1) * 16, c0 = (wv & 1) * 32;
    f32x4 acc[2] = {};
    #pragma unroll
    for (int ks = 0; ks < 2; ++ks) {
        short8v af = *reinterpret_cast<const short8v*>(&Tile[(r0 + lrow) * 72 + ks * 32 + lk]);
        #pragma unroll
        for (int fc = 0; fc < 2; ++fc) {
            short8v bf_ = *reinterpret_cast<const short8v*>(
                &Ws[(c0 + fc * 16 + lrow) * 72 + ks * 32 + lk]);
            acc[fc] = __builtin_amdgcn_mfma_f32_16x16x32_bf16(af, bf_, acc[fc], 0, 0, 0);
        }
    }
    __syncthreads();
    #pragma unroll
    for (int fc = 0; fc < 2; ++fc)
        #pragma unroll
        for (int j = 0; j < 4; ++j)
            Tile[(r0 + (lane >> 4) * 4 + j) * 72 + c0 + fc * 16 + lrow] = f2bf(acc[fc][j]);
    __syncthreads();
    {
        int r = t >> 3, c = t & 7;   // 256 threads = 32 rows x 8 chunks exactly
        *reinterpret_cast<ushort8v*>(
            hw2 + (size_t)(blockIdx.x * 4 + (r >> 3)) * 512 + (r & 7) * 64 + c * 8) =
            *reinterpret_cast<const ushort8v*>(&Tile[r * 72 + c * 8]);
    }
}

// ---------------------------------------------------------------- final gather + pool + FC
// hw2 bf16 [N][512]; gather, +self+bias, relu, dot fcw, reduce per b -> 8 partials/block.
__global__ __launch_bounds__(BLK) void k_gather_final(const unsigned short* __restrict__ hw,
                                                      const int* __restrict__ rs,
                                                      const int* __restrict__ cnt,
                                                      const int* __restrict__ csrc,
                                                      const float* __restrict__ cw,
                                                      const float* __restrict__ bias,
                                                      const float* __restrict__ fcw,
                                                      float* __restrict__ partial, int N) {
    const int w = threadIdx.x >> 6, lane = threadIdx.x & 63;
    const int n = blockIdx.x * 4 + w;
    float a[8];
    {
        const int beg = rs[n];
        const int deg = cnt[n];
        const float self = 1.0f / (1.0f + (float)deg);
        const float* bp = bias + (lane & 7) * 8;
        ushort8v v = *reinterpret_cast<const ushort8v*>(hw + (size_t)n * 512 + lane * 8);
        #pragma unroll
        for (int j = 0; j < 8; ++j) a[j] = fmaf(bf2f(v[j]), self, bp[j]);

        int i = 0;
        for (; i + 4 <= deg; i += 4) {
            int s0 = csrc[beg + i],     s1 = csrc[beg + i + 1];
            int s2 = csrc[beg + i + 2], s3 = csrc[beg + i + 3];
            float w0 = cw[beg + i],     w1 = cw[beg + i + 1];
            float w2 = cw[beg + i + 2], w3 = cw[beg + i + 3];
            EDGE_ACC(s0, w0); EDGE_ACC(s1, w1); EDGE_ACC(s2, w2); EDGE_ACC(s3, w3);
        }
        for (; i < deg; ++i) {
            int s0 = csrc[beg + i];
            float w0 = cw[beg + i];
            EDGE_ACC(s0, w0);
        }
    }
    __shared__ float sm[4][8];
    const float* fp = fcw + (lane & 7) * 8;
    float s = 0.f;
    #pragma unroll
    for (int j = 0; j < 8; ++j) s = fmaf(fmaxf(a[j], 0.f), fp[j], s);
    #pragma unroll
    for (int off = 1; off < 8; off <<= 1) s += __shfl_xor(s, off, 64);
    if ((lane & 7) == 0) sm[w][lane >> 3] = s;
    __syncthreads();
    if (threadIdx.x < 8)
        partial[(size_t)blockIdx.x * 8 + threadIdx.x] =
            sm[0][threadIdx.x] + sm[1][threadIdx.x] + sm[2][threadIdx.x] + sm[3][threadIdx.x];
}

// ---------------------------------------------------------------- finish
__global__ void k_finish(const float* __restrict__ partial, int nblk,
                         const float* __restrict__ addf, const float* __restrict__ fcw,
                         const float* __restrict__ fcb, float* __restrict__ out,
                         int N, int H) {
    int b = blockIdx.x;
    float s = 0.f;
    for (int i = threadIdx.x; i < nblk; i += BLK) s += partial[(size_t)i * 8 + b];
    __shared__ float sm[BLK / 64];
    int lane = threadIdx.x & 63, w = threadIdx.x >> 6;
    #pragma unroll
    for (int off = 32; off; off >>= 1) s += __shfl_down(s, off, 64);
    if (lane == 0) sm[w] = s;
    __syncthreads();
    if (threadIdx.x == 0) {
        float t = sm[0] + sm[1] + sm[2] + sm[3];
        out[b] = t / (float)N + addf[b] * fcw[H] + fcb[0];
    }
}

// ---------------------------------------------------------------- launch
extern "C" void kernel_launch(void* const* d_in, const int* in_sizes, int n_in,
                              void* d_out, int out_size, void* d_ws, size_t ws_size,
                              hipStream_t stream) {
    const float* x    = (const float*)d_in[0];
    const float* addf = (const float*)d_in[1];
    const int*   ei   = (const int*)d_in[2];
    const float* W1   = (const float*)d_in[3];
    const float* b1   = (const float*)d_in[4];
    const float* W2   = (const float*)d_in[5];
    const float* b2   = (const float*)d_in[6];
    const float* fcw  = (const float*)d_in[7];
    const float* fcb  = (const float*)d_in[8];
    float* out = (float*)d_out;

    const int B  = in_sizes[1];            // 8
    const int H  = in_sizes[4];            // 64
    const int IN = in_sizes[3] / H;        // 128
    const int E  = in_sizes[2] / 2;        // 320000
    const int N  = in_sizes[0] / (B * IN); // 20000
    const int* src = ei;
    const int* dst = ei + E;

    const int M = B * N;                   // 160000 node-major rows

    size_t bufsz = (size_t)M * H;
    unsigned short* bufA = (unsigned short*)d_ws;      // hw1 [N][512] bf16
    unsigned short* bufB = bufA + bufsz;               // hw2 [N][512] bf16
    int*   cnt   = (int*)(bufB + bufsz);
    int*   rs    = cnt + N;
    int*   cur   = rs + N;
    int*   csrc  = cur + N;
    float* cw    = (float*)(csrc + E);
    unsigned short* Wt1 = (unsigned short*)(cw + E);   // [64][128] bf16
    unsigned short* Wt2 = Wt1 + (size_t)H * IN;        // [64][64] bf16
    float* partial = (float*)(Wt2 + (size_t)H * H);

    const int nbN = (N + BLK - 1) / BLK;
    const int nbE = (E + BLK - 1) / BLK;
    const int nodes4 = (N + 3) / 4;        // N divisible by 4 here

    // CSR build + weight conversion
    k_init<<<dim3(nbN), dim3(BLK), 0, stream>>>(cnt, N, W1, W2, Wt1, Wt2, IN, H);
    k_count<<<dim3(nbE), dim3(BLK), 0, stream>>>(dst, cnt, E);
    k_scan_all<<<dim3(1), dim3(1024), 0, stream>>>(cnt, rs, cur, N);
    k_fill<<<dim3(nbE), dim3(BLK), 0, stream>>>(src, dst, cnt, cur, csrc, cw, E);

    // layer 1: hw1 = bf16(x) @ bf16(W1) -> bufA (node-major)
    k_gemm_mfma<128><<<dim3((M + 127) / 128), dim3(BLK), 0, stream>>>(
        x, Wt1, bufA, M, N, B);

    // fused: agg1 = gather(hw1)+self+b1; hw2 = relu(agg1) @ W2 -> bufB
    k_gather_gemm<<<dim3(nodes4), dim3(BLK), 0, stream>>>(
        bufA, rs, cnt, csrc, cw, b1, Wt2, bufB, N);

    // fused final: gather(hw2)+self+b2, relu, mean-pool, FC dot -> partials
    k_gather_final<<<dim3(nodes4), dim3(BLK), 0, stream>>>(
        bufB, rs, cnt, csrc, cw, b2, fcw, partial, N);

    k_finish<<<dim3(B), dim3(BLK), 0, stream>>>(partial, nodes4, addf, fcw, fcb, out, N, H);
}